// Round 4
// baseline (96.837 us; speedup 1.0000x reference)
//
#include <hip/hip_runtime.h>
#include <hip/hip_cooperative_groups.h>

namespace cg = cooperative_groups;

// Problem constants (match the reference)
#define T_DIM 160
#define B_DIM 64
#define C_DIM 6625
#define S_DIM 25
#define L_DIM 51            // 2*S+1
#define J_DIM 26            // distinct class slots: blank + 25 labels
#define TJ    (T_DIM * J_DIM)        // 4160
#define NEGV  (-1.0e30f)
#define LOG2E 1.4426950408889634f
#define LN2   0.6931471805599453f

#define GRID_BLKS 256

// ---------------------------------------------------------------------------
// Single cooperative kernel:
//   Phase A (all 256 blocks): dedup'd gather -> emit_ws[b][t][26], log2e-scaled.
//   grid.sync()
//   Phase B (blocks 0..63): burst slab to LDS, wave-0 alpha recurrence,
//                           per-sample nll -> per_ws[b].
//   grid.sync()
//   Phase C (block 0): 64-lane shuffle reduce -> out scalar.
// ---------------------------------------------------------------------------
__global__ __launch_bounds__(256)
void ctc_all(const float* __restrict__ preds,     // [T,B,C]
             const int*   __restrict__ targets,   // [B,S]
             const int*   __restrict__ tlen,      // [B]
             float*       __restrict__ emit_ws,   // [B,T,26]
             float*       __restrict__ per_ws,    // [B]
             float*       __restrict__ out)       // scalar
{
    cg::grid_group grid = cg::this_grid();
    const int tid = threadIdx.x;
    const int bid = blockIdx.x;

    __shared__ float emit_s[(T_DIM + 2) * J_DIM];   // +2 rows pad for prefetch

    // ---- Phase A: wide gather (grid-stride over B*T*26 elements) ----
    for (int w = bid * 256 + tid; w < B_DIM * TJ; w += GRID_BLKS * 256) {
        int b = w / TJ;
        int r = w - b * TJ;
        int t = r / J_DIM;
        int j = r - t * J_DIM;
        int cls = (j == 0) ? 0 : targets[b * S_DIM + j - 1];
        emit_s[0] = emit_s[0];  // no-op; keep LDS alive
        emit_ws[w] = preds[((size_t)t * B_DIM + b) * C_DIM + cls] * LOG2E;
    }
    grid.sync();

    // ---- Phase B: recurrence on blocks 0..63 ----
    if (bid < B_DIM) {
        // contiguous burst: 1040 float4s over 256 threads
        const float4* src = (const float4*)(emit_ws + (size_t)bid * TJ);
        float4*       dst = (float4*)emit_s;
        for (int i = tid; i < TJ / 4; i += 256) dst[i] = src[i];
        // zero the pad rows (avoid reading poison through prefetch)
        for (int i = TJ + tid; i < (T_DIM + 2) * J_DIM; i += 256) emit_s[i] = 0.0f;
        __syncthreads();

        if (tid < 64) {
            const int  l      = tid;                       // lattice position
            const bool active = (l < L_DIM);
            const int  j      = active ? ((l & 1) ? (l >> 1) + 1 : 0) : 0;
            const int  addr1  = ((l >= 1) ? l - 1 : l) << 2;
            const int  addr2  = ((l >= 2) ? l - 2 : l) << 2;
            const float mask2 = (l >= 1) ? 0.0f : NEGV;    // additive masks
            float mask3 = NEGV;
            if (active && (l & 1) && l >= 3) {
                int i = l >> 1;
                if (targets[bid * S_DIM + i] != targets[bid * S_DIM + i - 1])
                    mask3 = 0.0f;
            }

            float alpha = NEGV;                            // log2-domain
            if (l == 0) alpha = emit_s[0];
            if (l == 1) alpha = emit_s[1];

            float e1 = emit_s[1 * J_DIM + j];              // t=1
            float e2 = emit_s[2 * J_DIM + j];              // t=2
            for (int t = 1; t < T_DIM; ++t) {
                float e = active ? e1 : 0.0f;
                e1 = e2;
                e2 = emit_s[(t + 2) * J_DIM + j];          // pad rows make this safe
                float a1 = alpha;
                float a2 = __int_as_float(
                    __builtin_amdgcn_ds_bpermute(addr1, __float_as_int(alpha))) + mask2;
                float a3 = __int_as_float(
                    __builtin_amdgcn_ds_bpermute(addr2, __float_as_int(alpha))) + mask3;
                float m = fmaxf(fmaxf(a1, a2), a3);        // v_max3
                float s = exp2f(a1 - m) + exp2f(a2 - m) + exp2f(a3 - m);
                alpha = m + log2f(s) + e;
            }

            const int len = tlen[bid];
            const int idx = 2 * len;                       // in [10, 50]
            float l_last = __shfl(alpha, idx, 64);
            float l_prev = __shfl(alpha, idx - 1, 64);
            if (tid == 0) {
                float mm  = fmaxf(l_last, l_prev);
                float r2  = mm + log2f(exp2f(l_last - mm) + exp2f(l_prev - mm));
                float nll = -r2 * LN2;
                per_ws[bid] = (nll >= 1e29f) ? 0.0f : nll / (float)len;
            }
        }
    }
    grid.sync();

    // ---- Phase C: final mean on block 0 ----
    if (bid == 0 && tid < 64) {
        float v = per_ws[tid];
        #pragma unroll
        for (int off = 32; off > 0; off >>= 1)
            v += __shfl_down(v, off, 64);
        if (tid == 0) out[0] = v * (1.0f / B_DIM);
    }
}

// ---------------------------------------------------------------------------
// Fallback (R2 fused kernel) if cooperative launch is unavailable.
// ---------------------------------------------------------------------------
#define CHUNK  16
#define NCHUNK (T_DIM / CHUNK)
__global__ __launch_bounds__(256)
void ctc_alpha_fused(const float* __restrict__ preds,
                     const int*   __restrict__ targets,
                     const int*   __restrict__ tlen,
                     float*       __restrict__ out)
{
    const int b   = blockIdx.x;
    const int tid = threadIdx.x;
    __shared__ float emit_f[T_DIM * L_DIM];
    __shared__ int   ext_f[L_DIM];
    if (tid < L_DIM) {
        ext_f[tid] = (tid & 1) ? targets[b * S_DIM + (tid >> 1)] : 0;
    }
    __syncthreads();
    const size_t row_stride = (size_t)B_DIM * C_DIM;
    const float* pb = preds + (size_t)b * C_DIM;
    for (int flat = tid; flat < CHUNK * L_DIM; flat += 256) {
        int t = flat / L_DIM;
        int l = flat - t * L_DIM;
        emit_f[flat] = pb[(size_t)t * row_stride + ext_f[l]] * LOG2E;
    }
    __syncthreads();
    const int l = tid;
    const int l_eff = (l < L_DIM) ? l : (L_DIM - 1);
    const int addr1 = ((l >= 1) ? l - 1 : 0) << 2;
    const int addr2 = ((l >= 2) ? l - 2 : 0) << 2;
    bool skipf = false;
    if (tid < 64 && (l & 1) && l >= 3 && l < L_DIM) {
        int i = l >> 1;
        skipf = (targets[b * S_DIM + i] != targets[b * S_DIM + i - 1]);
    }
    float alpha = NEGV;
    if (tid == 0) alpha = emit_f[0];
    if (tid == 1) alpha = emit_f[1];
    int t = 1;
    for (int c = 0; c < NCHUNK; ++c) {
        if (tid >= 64) {
            if (c + 1 < NCHUNK) {
                const int base = (c + 1) * CHUNK * L_DIM;
                const int t0   = (c + 1) * CHUNK;
                for (int flat = tid - 64; flat < CHUNK * L_DIM; flat += 192) {
                    int tt = flat / L_DIM;
                    int ll = flat - tt * L_DIM;
                    emit_f[base + flat] =
                        pb[(size_t)(t0 + tt) * row_stride + ext_f[ll]] * LOG2E;
                }
            }
        } else {
            const int tend = (c + 1) * CHUNK;
            for (; t < tend; ++t) {
                float a1 = alpha;
                float a2 = __int_as_float(
                    __builtin_amdgcn_ds_bpermute(addr1, __float_as_int(alpha)));
                float a3 = __int_as_float(
                    __builtin_amdgcn_ds_bpermute(addr2, __float_as_int(alpha)));
                if (l < 1)  a2 = NEGV;
                if (!skipf) a3 = NEGV;
                float m = fmaxf(fmaxf(a1, a2), a3);
                float s = exp2f(a1 - m) + exp2f(a2 - m) + exp2f(a3 - m);
                alpha = m + log2f(s) + emit_f[t * L_DIM + l_eff];
            }
        }
        __syncthreads();
    }
    if (tid < 64) {
        const int len = tlen[b];
        const int idx = 2 * len;
        float l_last = __shfl(alpha, idx, 64);
        float l_prev = __shfl(alpha, idx - 1, 64);
        if (tid == 0) {
            float m   = fmaxf(l_last, l_prev);
            float r2  = m + log2f(exp2f(l_last - m) + exp2f(l_prev - m));
            float nll = -r2 * LN2;
            float per = (nll >= 1e29f) ? 0.0f : nll / (float)len;
            atomicAdd(out, per * (1.0f / B_DIM));
        }
    }
}

extern "C" void kernel_launch(void* const* d_in, const int* in_sizes, int n_in,
                              void* d_out, int out_size, void* d_ws, size_t ws_size,
                              hipStream_t stream)
{
    const float* preds   = (const float*)d_in[0];   // [T,B,C] fp32
    const int*   targets = (const int*)d_in[1];     // [B,S]
    const int*   tlen    = (const int*)d_in[2];     // [B]
    float* out = (float*)d_out;                     // scalar

    const size_t ws_needed = (size_t)(B_DIM * TJ + B_DIM) * sizeof(float);
    if (ws_size >= ws_needed) {
        float* emit_ws = (float*)d_ws;
        float* per_ws  = emit_ws + (size_t)B_DIM * TJ;
        void* args[] = {(void*)&preds, (void*)&targets, (void*)&tlen,
                        (void*)&emit_ws, (void*)&per_ws, (void*)&out};
        hipError_t rc = hipLaunchCooperativeKernel(
            (const void*)ctc_all, dim3(GRID_BLKS), dim3(256), args, 0, stream);
        if (rc == hipSuccess) return;
    }
    // Fallback: proven two-dispatch path
    hipMemsetAsync(out, 0, sizeof(float), stream);
    ctc_alpha_fused<<<B_DIM, 256, 0, stream>>>(preds, targets, tlen, out);
}

// Round 5
// 23.071 us; speedup vs baseline: 4.1975x; 4.1975x over previous
//
#include <hip/hip_runtime.h>

// Problem constants (match the reference)
#define T_DIM 160
#define B_DIM 64
#define C_DIM 6625
#define S_DIM 25
#define L_DIM 51            // 2*S+1
#define J_DIM 26            // distinct class slots: blank + 25 labels
#define NEGV  (-1.0e30f)
#define LOG2E 1.4426950408889634f
#define LN2   0.6931471805599453f
#define CHUNK  32
#define NCHUNK (T_DIM / CHUNK)   // 5

// lane l gets x from lane l-1 via DPP wave_shr:1 (~5 cy, vs ~35 cy ds_bpermute).
// Invalid lane 0 receives `fill` through the DPP old-operand (bound_ctrl=0).
__device__ __forceinline__ float wave_shr1(float x, float fill) {
    return __int_as_float(__builtin_amdgcn_update_dpp(
        __float_as_int(fill), __float_as_int(x),
        0x138 /* wave_shr:1 */, 0xF, 0xF, false));
}

// One block per batch element.
//  wave 0: CTC alpha recurrence in log2 domain, lane l = lattice position.
//  waves 1..3: stage chunk c+1's dedup'd emissions (26 classes) into LDS
//  while wave 0 computes chunk c.
__global__ __launch_bounds__(256)
void ctc_alpha_fused(const float* __restrict__ preds,     // [T,B,C]
                     const int*   __restrict__ targets,   // [B,S]
                     const int*   __restrict__ tlen,      // [B]
                     float*       __restrict__ out)       // scalar (pre-zeroed)
{
    const int b   = blockIdx.x;
    const int tid = threadIdx.x;

    __shared__ float emit_s[T_DIM * J_DIM];   // 160*26*4 = 16640 B
    __shared__ int   cls_s[J_DIM];

    if (tid < J_DIM) cls_s[tid] = (tid == 0) ? 0 : targets[b * S_DIM + tid - 1];
    __syncthreads();

    const size_t row = (size_t)B_DIM * C_DIM;
    const float* pb  = preds + (size_t)b * C_DIM;

    // Prologue: stage chunk 0 with all 256 threads (26 distinct classes only).
    for (int f = tid; f < CHUNK * J_DIM; f += 256) {
        int t = f / J_DIM;
        int j = f - t * J_DIM;
        emit_s[f] = pb[(size_t)t * row + cls_s[j]] * LOG2E;
    }
    __syncthreads();

    // Per-lane recurrence constants (wave 0)
    const int  l      = tid;
    const bool active = (l < L_DIM);
    const int  j      = active ? ((l & 1) ? (l >> 1) + 1 : 0) : 0;
    float mask3 = NEGV;                 // additive skip mask: 0 if skip allowed
    if (active && (l & 1) && l >= 3) {
        int i = l >> 1;
        if (targets[b * S_DIM + i] != targets[b * S_DIM + i - 1]) mask3 = 0.0f;
    }

    float alpha = NEGV;                 // log2-domain alpha
    if (l == 0) alpha = emit_s[0];      // t=0 blank slot
    if (l == 1) alpha = emit_s[1];      // t=0 first-label slot

    for (int c = 0; c < NCHUNK; ++c) {
        if (tid >= 64) {
            // Stage chunk c+1 while wave 0 computes chunk c.
            if (c + 1 < NCHUNK) {
                const int base = (c + 1) * CHUNK * J_DIM;
                const int t0   = (c + 1) * CHUNK;
                for (int f = tid - 64; f < CHUNK * J_DIM; f += 192) {
                    int tt = f / J_DIM;
                    int jj = f - tt * J_DIM;
                    emit_s[base + f] =
                        pb[(size_t)(t0 + tt) * row + cls_s[jj]] * LOG2E;
                }
            }
        } else {
            const int cbase = c * CHUNK * J_DIM;
            #pragma unroll
            for (int k = 0; k < CHUNK; ++k) {
                const int t = c * CHUNK + k;
                if (t == 0) continue;                    // only skips once (c=0,k=0)
                // emission read is alpha-independent: issues ahead of the chain
                float e  = active ? emit_s[cbase + k * J_DIM + j] : 0.0f;
                float a2 = wave_shr1(alpha, NEGV);       // alpha[l-1]
                float a3 = wave_shr1(a2, NEGV) + mask3;  // alpha[l-2] (masked)
                float m  = fmaxf(fmaxf(alpha, a2), a3);  // v_max3
                float s  = __builtin_amdgcn_exp2f(alpha - m)
                         + __builtin_amdgcn_exp2f(a2 - m)
                         + __builtin_amdgcn_exp2f(a3 - m);
                alpha = m + __builtin_amdgcn_logf(s) + e;
            }
        }
        __syncthreads();
    }

    // nll = -ln2 * log2addexp2(alpha[2*len], alpha[2*len-1])
    if (tid < 64) {
        const int len = tlen[b];
        const int idx = 2 * len;                         // in [10, 50]
        float l_last = __shfl(alpha, idx, 64);
        float l_prev = __shfl(alpha, idx - 1, 64);
        if (tid == 0) {
            float m   = fmaxf(l_last, l_prev);
            float r2  = m + __builtin_amdgcn_logf(
                             __builtin_amdgcn_exp2f(l_last - m)
                           + __builtin_amdgcn_exp2f(l_prev - m));
            float nll = -r2 * LN2;
            float per = (nll >= 1e29f) ? 0.0f : nll / (float)len;
            atomicAdd(out, per * (1.0f / B_DIM));
        }
    }
}

extern "C" void kernel_launch(void* const* d_in, const int* in_sizes, int n_in,
                              void* d_out, int out_size, void* d_ws, size_t ws_size,
                              hipStream_t stream)
{
    const float* preds   = (const float*)d_in[0];   // [T,B,C] fp32
    const int*   targets = (const int*)d_in[1];     // [B,S]
    const int*   tlen    = (const int*)d_in[2];     // [B]
    float* out = (float*)d_out;                     // scalar

    hipMemsetAsync(out, 0, sizeof(float), stream);  // out accumulates atomically
    ctc_alpha_fused<<<B_DIM, 256, 0, stream>>>(preds, targets, tlen, out);
}